// Round 1
// baseline (123.915 us; speedup 1.0000x reference)
//
#include <hip/hip_runtime.h>
#include <math.h>

#define DIM  512
#define H2   512
#define BSZ  384

// ---------------------------------------------------------------------------
// ws layout (floats):
//   hmu : 384*512   @ 0        relu(x@w1mu + b1mu)
//   hlv : 384*512   @ 196608
//   m1p : 6*512     @ 393216   y column-sum partials
//   m2p : 6*512     @ 396288   y column-sumsq partials
//   part: 192 dbl   @ 399360   (byte 1597440, 8B aligned) per-block partials
//   ctr : 1 uint    @ 399744   arrival counter (zeroed by k_layer1 each launch)
// total ~1.6 MB
//
// Structure: 2 kernels.
//   K1: layer-1 GEMMs both branches + y column moments (198 blocks) — proven.
//   K2: layer-2 GEMMs (mu half-block + lv half-block on the SAME 16x64 (i,j)
//       tile) + fused epilogue (bias/tanh/exp/moment math in-register, 4KB
//       LDS exchange of inv_var) + fence/counter last-block final reduce.
// ---------------------------------------------------------------------------

template<bool RELU>
__device__ __forceinline__ void gemm_tile(
    const float* __restrict__ A, const float* __restrict__ B,
    const float* __restrict__ bias, float* __restrict__ C,
    int m0, int n0,
    float (*As)[34], float (*Bs)[64])
{
    const int tid = threadIdx.x;
    const int tx = tid & 15;        // col group: n0 + tx*4
    const int ty = tid >> 4;        // rows: m0 + ty*2 + {0,1}

    const int r_a  = tid >> 3;      // 0..31  A-tile row
    const int kg_a = tid & 7;       // 0..7   A-tile k-group (4 floats)
    const int kr_b = tid >> 4;      // 0..15  B-tile row (and +16)
    const int cg_b = tid & 15;      // 0..15  B-tile col group

    float acc[2][4] = {};

    float4 a_pf  = *(const float4*)&A[(size_t)(m0 + r_a) * 512 + kg_a * 4];
    float4 b_pf0 = *(const float4*)&B[(size_t)kr_b        * 512 + n0 + cg_b * 4];
    float4 b_pf1 = *(const float4*)&B[(size_t)(kr_b + 16) * 512 + n0 + cg_b * 4];

    for (int it = 0; it < 16; ++it) {
        __syncthreads();
        {
            float av[4];
            *(float4*)av = a_pf;
            #pragma unroll
            for (int j = 0; j < 4; ++j) As[kg_a * 4 + j][r_a] = av[j];
            *(float4*)&Bs[kr_b][cg_b * 4]      = b_pf0;
            *(float4*)&Bs[kr_b + 16][cg_b * 4] = b_pf1;
        }
        __syncthreads();

        if (it < 15) {
            const int k0n = (it + 1) * 32;
            a_pf  = *(const float4*)&A[(size_t)(m0 + r_a) * 512 + k0n + kg_a * 4];
            b_pf0 = *(const float4*)&B[(size_t)(k0n + kr_b)      * 512 + n0 + cg_b * 4];
            b_pf1 = *(const float4*)&B[(size_t)(k0n + kr_b + 16) * 512 + n0 + cg_b * 4];
        }

        #pragma unroll
        for (int kk = 0; kk < 32; ++kk) {
            const float a0 = As[kk][ty * 2 + 0];
            const float a1 = As[kk][ty * 2 + 1];
            const float4 bv = *(const float4*)&Bs[kk][tx * 4];
            acc[0][0] += a0 * bv.x; acc[0][1] += a0 * bv.y;
            acc[0][2] += a0 * bv.z; acc[0][3] += a0 * bv.w;
            acc[1][0] += a1 * bv.x; acc[1][1] += a1 * bv.y;
            acc[1][2] += a1 * bv.z; acc[1][3] += a1 * bv.w;
        }
    }

    float bb[4] = {0.f, 0.f, 0.f, 0.f};
    if (RELU) *(float4*)bb = *(const float4*)&bias[n0 + tx * 4];
    #pragma unroll
    for (int i = 0; i < 2; ++i) {
        float4 o;
        if (RELU) {
            o.x = fmaxf(acc[i][0] + bb[0], 0.f);
            o.y = fmaxf(acc[i][1] + bb[1], 0.f);
            o.z = fmaxf(acc[i][2] + bb[2], 0.f);
            o.w = fmaxf(acc[i][3] + bb[3], 0.f);
        } else {
            o.x = acc[i][0]; o.y = acc[i][1]; o.z = acc[i][2]; o.w = acc[i][3];
        }
        *(float4*)&C[(size_t)(m0 + ty * 2 + i) * 512 + n0 + tx * 4] = o;
    }
}

// Kernel 1: layer-1 GEMMs for both branches (blocks 0..191) + y column-moment
// partial blocks (192..197). Block 192 also zeroes the K2 arrival counter.
__global__ __launch_bounds__(256) void k_layer1(
    const float* __restrict__ x,
    const float* __restrict__ w1mu, const float* __restrict__ b1mu,
    const float* __restrict__ w1lv, const float* __restrict__ b1lv,
    const float* __restrict__ y,
    float* __restrict__ hmu, float* __restrict__ hlv,
    float* __restrict__ m1p, float* __restrict__ m2p,
    unsigned* __restrict__ ctr)
{
    __shared__ float As[32][34];
    __shared__ float Bs[32][64];

    const int b = blockIdx.x;
    const int tid = threadIdx.x;

    if (b >= 192) {
        __shared__ float r1[2][512];
        __shared__ float r2[2][512];
        const int sb = b - 192;
        if (sb == 0 && tid == 0) *ctr = 0u;   // reset K2 arrival counter
        const int c4 = tid & 127;
        const int rh = tid >> 7;
        const int r0 = sb * 64 + rh * 32;
        float s1[4] = {0.f, 0.f, 0.f, 0.f};
        float s2[4] = {0.f, 0.f, 0.f, 0.f};
        for (int r = 0; r < 32; ++r) {
            float v[4];
            *(float4*)v = *(const float4*)&y[(size_t)(r0 + r) * 512 + c4 * 4];
            #pragma unroll
            for (int j = 0; j < 4; ++j) { s1[j] += v[j]; s2[j] += v[j] * v[j]; }
        }
        #pragma unroll
        for (int j = 0; j < 4; ++j) { r1[rh][c4 * 4 + j] = s1[j]; r2[rh][c4 * 4 + j] = s2[j]; }
        __syncthreads();
        if (rh == 0) {
            float4 o1, o2;
            o1.x = s1[0] + r1[1][c4 * 4 + 0]; o1.y = s1[1] + r1[1][c4 * 4 + 1];
            o1.z = s1[2] + r1[1][c4 * 4 + 2]; o1.w = s1[3] + r1[1][c4 * 4 + 3];
            o2.x = s2[0] + r2[1][c4 * 4 + 0]; o2.y = s2[1] + r2[1][c4 * 4 + 1];
            o2.z = s2[2] + r2[1][c4 * 4 + 2]; o2.w = s2[3] + r2[1][c4 * 4 + 3];
            *(float4*)&m1p[sb * 512 + c4 * 4] = o1;
            *(float4*)&m2p[sb * 512 + c4 * 4] = o2;
        }
        return;
    }

    const int branch = b >= 96 ? 1 : 0;
    const int idx = branch ? b - 96 : b;
    const int m0 = (idx >> 3) * 32;
    const int n0 = (idx & 7) * 64;

    if (branch == 0)
        gemm_tile<true>(x, w1mu, b1mu, hmu, m0, n0, As, Bs);
    else
        gemm_tile<true>(x, w1lv, b1lv, hlv, m0, n0, As, Bs);
}

// Kernel 2 (fused): layer-2 GEMMs + epilogue + final reduction.
// 192 blocks x 256 threads. Threads 0..127 compute the mu 16x64 tile,
// threads 128..255 the lv 16x64 tile at the SAME (i,j). lv half exchanges
// inv_var through LDS; mu half applies the loss math; fence+counter gives
// the last block the 192-partial final reduce.
__global__ __launch_bounds__(256) void k2_fused(
    const float* __restrict__ hmu, const float* __restrict__ hlv,
    const float* __restrict__ w2mu, const float* __restrict__ w2lv,
    const float* __restrict__ b2mu, const float* __restrict__ b2lv,
    const float* __restrict__ y,
    const float* __restrict__ m1p, const float* __restrict__ m2p,
    double* __restrict__ partials, unsigned* __restrict__ ctr,
    float* __restrict__ out)
{
    __shared__ float As[2][32][18];   // k-major A tiles, +2 pad
    __shared__ float Bs[2][32][64];
    __shared__ float ivs[16][64];     // inv_var exchange
    __shared__ double wsum[4];
    __shared__ int lastFlag;

    const int b   = blockIdx.x;
    const int tid = threadIdx.x;
    const int half = tid >> 7;        // 0 = mu, 1 = lv
    const int t    = tid & 127;

    const int m0 = (b >> 3) * 16;     // 24 row tiles
    const int n0 = (b & 7) * 64;      // 8 col tiles

    const float* __restrict__ A = half ? hlv : hmu;
    const float* __restrict__ B = half ? w2lv : w2mu;
    float (*as)[18] = As[half];
    float (*bs)[64] = Bs[half];

    // staging assignments (per 128-thread half)
    const int r_a  = t >> 3;          // 0..15 A row
    const int kg_a = t & 7;           // 0..7  A k-group
    const int kr_b = t >> 4;          // 0..7  B row (and +8,+16,+24)
    const int cg_b = t & 15;

    // compute assignments
    const int tx = t & 15;            // cols n0 + tx*4
    const int ty = t >> 4;            // rows m0 + ty*2 + {0,1}

    float acc[2][4] = {};

    float4 a_pf = *(const float4*)&A[(size_t)(m0 + r_a) * 512 + kg_a * 4];
    float4 b_pf[4];
    #pragma unroll
    for (int q = 0; q < 4; ++q)
        b_pf[q] = *(const float4*)&B[(size_t)(kr_b + q * 8) * 512 + n0 + cg_b * 4];

    for (int it = 0; it < 16; ++it) {
        __syncthreads();
        {
            float av[4];
            *(float4*)av = a_pf;
            #pragma unroll
            for (int j = 0; j < 4; ++j) as[kg_a * 4 + j][r_a] = av[j];
            #pragma unroll
            for (int q = 0; q < 4; ++q)
                *(float4*)&bs[kr_b + q * 8][cg_b * 4] = b_pf[q];
        }
        __syncthreads();

        if (it < 15) {
            const int k0n = (it + 1) * 32;
            a_pf = *(const float4*)&A[(size_t)(m0 + r_a) * 512 + k0n + kg_a * 4];
            #pragma unroll
            for (int q = 0; q < 4; ++q)
                b_pf[q] = *(const float4*)&B[(size_t)(k0n + kr_b + q * 8) * 512 + n0 + cg_b * 4];
        }

        #pragma unroll
        for (int kk = 0; kk < 32; ++kk) {
            const float a0 = as[kk][ty * 2 + 0];
            const float a1 = as[kk][ty * 2 + 1];
            const float4 bv = *(const float4*)&bs[kk][tx * 4];
            acc[0][0] += a0 * bv.x; acc[0][1] += a0 * bv.y;
            acc[0][2] += a0 * bv.z; acc[0][3] += a0 * bv.w;
            acc[1][0] += a1 * bv.x; acc[1][1] += a1 * bv.y;
            acc[1][2] += a1 * bv.z; acc[1][3] += a1 * bv.w;
        }
    }

    // ---- fused epilogue ----
    float tsum = 0.f;
    float bm[4], s1[4], s2[4], yv0[4], yv1[4];

    if (half) {
        // lv half: lv = tanh(g + b2lv), inv_var = exp(-lv) -> LDS
        float bl[4];
        *(float4*)bl = *(const float4*)&b2lv[n0 + tx * 4];
        #pragma unroll
        for (int i = 0; i < 2; ++i) {
            #pragma unroll
            for (int j = 0; j < 4; ++j) {
                const float lv = tanhf(acc[i][j] + bl[j]);
                ivs[ty * 2 + i][tx * 4 + j] = expf(-lv);
            }
        }
    } else {
        // mu half: gather bias, y rows and column moments (overlaps lv tanh)
        *(float4*)bm = *(const float4*)&b2mu[n0 + tx * 4];
        #pragma unroll
        for (int j = 0; j < 4; ++j) { s1[j] = 0.f; s2[j] = 0.f; }
        #pragma unroll
        for (int p = 0; p < 6; ++p) {
            float p1[4], p2[4];
            *(float4*)p1 = *(const float4*)&m1p[p * 512 + n0 + tx * 4];
            *(float4*)p2 = *(const float4*)&m2p[p * 512 + n0 + tx * 4];
            #pragma unroll
            for (int j = 0; j < 4; ++j) { s1[j] += p1[j]; s2[j] += p2[j]; }
        }
        *(float4*)yv0 = *(const float4*)&y[(size_t)(m0 + ty * 2 + 0) * 512 + n0 + tx * 4];
        *(float4*)yv1 = *(const float4*)&y[(size_t)(m0 + ty * 2 + 1) * 512 + n0 + tx * 4];
    }
    __syncthreads();

    if (!half) {
        const float inv_b = 1.0f / (float)BSZ;
        #pragma unroll
        for (int i = 0; i < 2; ++i) {
            const float* yv = i ? yv1 : yv0;
            #pragma unroll
            for (int j = 0; j < 4; ++j) {
                const float m1 = s1[j] * inv_b;
                const float m2 = s2[j] * inv_b;
                const float mu = acc[i][j] + bm[j];
                const float iv = ivs[ty * 2 + i][tx * 4 + j];
                tsum += iv * ((yv[j] * yv[j] - m2) + 2.f * mu * (m1 - yv[j]));
            }
        }
    }

    // block reduction (lv half contributes 0)
    float s = tsum;
    #pragma unroll
    for (int off = 32; off > 0; off >>= 1) s += __shfl_down(s, off);
    if ((tid & 63) == 0) wsum[tid >> 6] = (double)s;
    __syncthreads();
    if (tid == 0) {
        partials[b] = wsum[0] + wsum[1] + wsum[2] + wsum[3];
        __threadfence();
        const unsigned old = atomicAdd(ctr, 1u);
        lastFlag = (old == 191u);
    }
    __syncthreads();

    if (lastFlag) {
        __threadfence();  // acquire: make all partials visible
        if (tid < 64) {
            double v = partials[tid] + partials[tid + 64] + partials[tid + 128];
            #pragma unroll
            for (int off = 32; off > 0; off >>= 1) v += __shfl_down(v, off);
            if (tid == 0) {
                // C0 = log1p(exp(-20)/383) — the broadcast-bug logsumexp constant
                const double C0 = 5.381602146862063e-12;
                out[0] = (float)(-0.5 * v / (double)BSZ - C0);
            }
        }
    }
}

extern "C" void kernel_launch(void* const* d_in, const int* in_sizes, int n_in,
                              void* d_out, int out_size, void* d_ws, size_t ws_size,
                              hipStream_t stream) {
    const float* x    = (const float*)d_in[0];
    const float* y    = (const float*)d_in[1];
    const float* w1mu = (const float*)d_in[2];
    const float* b1mu = (const float*)d_in[3];
    const float* w2mu = (const float*)d_in[4];
    const float* b2mu = (const float*)d_in[5];
    const float* w1lv = (const float*)d_in[6];
    const float* b1lv = (const float*)d_in[7];
    const float* w2lv = (const float*)d_in[8];
    const float* b2lv = (const float*)d_in[9];
    float* out = (float*)d_out;

    float* ws = (float*)d_ws;
    float* hmu = ws;
    float* hlv = ws + 196608;
    float* m1p = ws + 393216;
    float* m2p = ws + 396288;
    double* partials = (double*)(ws + 399360);
    unsigned* ctr = (unsigned*)(ws + 399744);

    k_layer1<<<198, 256, 0, stream>>>(x, w1mu, b1mu, w1lv, b1lv, y,
                                      hmu, hlv, m1p, m2p, ctr);
    k2_fused<<<192, 256, 0, stream>>>(hmu, hlv, w2mu, w2lv, b2mu, b2lv, y,
                                      m1p, m2p, partials, ctr, out);
}

// Round 2
// 116.403 us; speedup vs baseline: 1.0645x; 1.0645x over previous
//
#include <hip/hip_runtime.h>
#include <math.h>

#define DIM  512
#define H2   512
#define BSZ  384

// ---------------------------------------------------------------------------
// ws layout (floats):
//   hmu : 384*512  @ 0        relu(x@w1mu + b1mu)
//   hlv : 384*512  @ 196608
//   gmu : 384*512  @ 393216   hmu@w2mu (no bias)
//   glv : 384*512  @ 589824
//   m1p : 6*512    @ 786432   y column-sum partials
//   m2p : 6*512    @ 789504   y column-sumsq partials
//   m1f : 512      @ 792576   column means of y
//   m2f : 512      @ 793088   column mean-squares of y
//   part: 192 dbl  @ 793600   (byte 3174400, 8B aligned)
//   ctr : 1 uint   @ 793984   arrival counter (zeroed by k_l1 each launch)
//
// Structure: 3 kernels, all sized for wave-count (latency hiding), not tile
// efficiency — the problem is tiny (805 MFLOP) and latency-bound.
//   K1: layer-1 GEMMs, 384 tile-blocks (32x32 tile, 4-way K-split, 4x4
//       micro) + 6 y-moment blocks. 390x256.
//   K2: layer-2 GEMMs, same shape, + 1 moment-finalize block. 385x256.
//   K3: elementwise epilogue, 192x256, 1 float4/thread, fused final reduce
//       via fence+counter (proven in round 1).
// ---------------------------------------------------------------------------

// One block = one 32x32 C tile. Wave w (of 4) computes the partial product
// over K in [w*128, w*128+128) into private LDS-staged tiles; partials are
// combined through LDS by wave 0 (ascending w, closest to sequential-K
// rounding). Per-lane: 4x4 micro-tile, float4 LDS fragment reads (8-way
// broadcast, conflict-free with the 36-float padded stride).
template<bool RELU>
__device__ __forceinline__ void gemm_tile32(
    const float* __restrict__ A, const float* __restrict__ B,
    const float* __restrict__ bias, float* __restrict__ C,
    int m0, int n0,
    float (*As4)[32][36], float (*Bs4)[32][36], float (*Cs)[1024])
{
    const int tid = threadIdx.x;
    const int w  = tid >> 6;        // wave 0..3 = K-split index
    const int t  = tid & 63;
    const int lx = t & 7;           // cols n0 + lx*4 .. +3
    const int ly = t >> 3;          // rows m0 + ly*4 .. +3
    const int kg = t & 7;           // staging k-group (4 floats)
    const int rq = t >> 3;          // staging row base (0..7, +q*8)
    const int kbase = w * 128;

    float (*as)[36] = As4[w];
    float (*bs)[36] = Bs4[w];

    float acc[4][4] = {};
    float4 apf[4], bpf[4];
    #pragma unroll
    for (int q = 0; q < 4; ++q) {
        apf[q] = *(const float4*)&A[(size_t)(m0 + rq + q * 8) * 512 + kbase + kg * 4];
        bpf[q] = *(const float4*)&B[(size_t)(kbase + rq + q * 8) * 512 + n0 + kg * 4];
    }

    for (int it = 0; it < 4; ++it) {
        __syncthreads();
        #pragma unroll
        for (int q = 0; q < 4; ++q) {
            float av[4];
            *(float4*)av = apf[q];
            #pragma unroll
            for (int j = 0; j < 4; ++j) as[kg * 4 + j][rq + q * 8] = av[j];  // k-major A
            *(float4*)&bs[rq + q * 8][kg * 4] = bpf[q];
        }
        __syncthreads();

        if (it < 3) {   // next-iter loads overlap compute below
            const int k0 = kbase + (it + 1) * 32;
            #pragma unroll
            for (int q = 0; q < 4; ++q) {
                apf[q] = *(const float4*)&A[(size_t)(m0 + rq + q * 8) * 512 + k0 + kg * 4];
                bpf[q] = *(const float4*)&B[(size_t)(k0 + rq + q * 8) * 512 + n0 + kg * 4];
            }
        }

        #pragma unroll
        for (int kk = 0; kk < 32; ++kk) {
            float av[4], bv[4];
            *(float4*)av = *(const float4*)&as[kk][ly * 4];
            *(float4*)bv = *(const float4*)&bs[kk][lx * 4];
            #pragma unroll
            for (int i = 0; i < 4; ++i)
                #pragma unroll
                for (int j = 0; j < 4; ++j)
                    acc[i][j] += av[i] * bv[j];
        }
    }

    // K-split combine: waves 1..3 park partials in LDS, wave 0 sums (w asc).
    if (w) {
        #pragma unroll
        for (int i = 0; i < 4; ++i)
            *(float4*)&Cs[w - 1][(ly * 4 + i) * 32 + lx * 4] = *(const float4*)&acc[i][0];
    }
    __syncthreads();
    if (!w) {
        #pragma unroll
        for (int q = 0; q < 3; ++q)
            #pragma unroll
            for (int i = 0; i < 4; ++i) {
                float cv[4];
                *(float4*)cv = *(const float4*)&Cs[q][(ly * 4 + i) * 32 + lx * 4];
                #pragma unroll
                for (int j = 0; j < 4; ++j) acc[i][j] += cv[j];
            }
        float bb[4] = {0.f, 0.f, 0.f, 0.f};
        if (RELU) *(float4*)bb = *(const float4*)&bias[n0 + lx * 4];
        #pragma unroll
        for (int i = 0; i < 4; ++i) {
            float4 o;
            if (RELU) {
                o.x = fmaxf(acc[i][0] + bb[0], 0.f);
                o.y = fmaxf(acc[i][1] + bb[1], 0.f);
                o.z = fmaxf(acc[i][2] + bb[2], 0.f);
                o.w = fmaxf(acc[i][3] + bb[3], 0.f);
            } else {
                o.x = acc[i][0]; o.y = acc[i][1]; o.z = acc[i][2]; o.w = acc[i][3];
            }
            *(float4*)&C[(size_t)(m0 + ly * 4 + i) * 512 + n0 + lx * 4] = o;
        }
    }
}

// Kernel 1: layer-1 GEMMs for both branches (blocks 0..383: 2 x 12 x 16
// tiles) + y column-moment partials (blocks 384..389). Block 384 zeroes ctr.
__global__ __launch_bounds__(256) void k_l1(
    const float* __restrict__ x,
    const float* __restrict__ w1mu, const float* __restrict__ b1mu,
    const float* __restrict__ w1lv, const float* __restrict__ b1lv,
    const float* __restrict__ y,
    float* __restrict__ hmu, float* __restrict__ hlv,
    float* __restrict__ m1p, float* __restrict__ m2p,
    unsigned* __restrict__ ctr)
{
    __shared__ float As[4][32][36];
    __shared__ float Bs[4][32][36];
    __shared__ float Cs[3][1024];

    const int b = blockIdx.x;
    const int tid = threadIdx.x;

    if (b >= 384) {
        __shared__ float r1[2][512];
        __shared__ float r2[2][512];
        const int sb = b - 384;
        if (sb == 0 && tid == 0) *ctr = 0u;   // reset K3 arrival counter
        const int c4 = tid & 127;
        const int rh = tid >> 7;
        const int r0 = sb * 64 + rh * 32;
        float s1[4] = {0.f, 0.f, 0.f, 0.f};
        float s2[4] = {0.f, 0.f, 0.f, 0.f};
        for (int r = 0; r < 32; ++r) {
            float v[4];
            *(float4*)v = *(const float4*)&y[(size_t)(r0 + r) * 512 + c4 * 4];
            #pragma unroll
            for (int j = 0; j < 4; ++j) { s1[j] += v[j]; s2[j] += v[j] * v[j]; }
        }
        #pragma unroll
        for (int j = 0; j < 4; ++j) { r1[rh][c4 * 4 + j] = s1[j]; r2[rh][c4 * 4 + j] = s2[j]; }
        __syncthreads();
        if (rh == 0) {
            float4 o1, o2;
            o1.x = s1[0] + r1[1][c4 * 4 + 0]; o1.y = s1[1] + r1[1][c4 * 4 + 1];
            o1.z = s1[2] + r1[1][c4 * 4 + 2]; o1.w = s1[3] + r1[1][c4 * 4 + 3];
            o2.x = s2[0] + r2[1][c4 * 4 + 0]; o2.y = s2[1] + r2[1][c4 * 4 + 1];
            o2.z = s2[2] + r2[1][c4 * 4 + 2]; o2.w = s2[3] + r2[1][c4 * 4 + 3];
            *(float4*)&m1p[sb * 512 + c4 * 4] = o1;
            *(float4*)&m2p[sb * 512 + c4 * 4] = o2;
        }
        return;
    }

    const int branch = b >= 192;
    const int idx = branch ? b - 192 : b;
    const int m0 = (idx >> 4) * 32;   // 12 row tiles
    const int n0 = (idx & 15) * 32;   // 16 col tiles

    if (!branch)
        gemm_tile32<true>(x, w1mu, b1mu, hmu, m0, n0, As, Bs, Cs);
    else
        gemm_tile32<true>(x, w1lv, b1lv, hlv, m0, n0, As, Bs, Cs);
}

// Kernel 2: layer-2 GEMMs (blocks 0..383), raw (bias deferred to K3), plus
// block 384 finalizing the y column means.
__global__ __launch_bounds__(256) void k_l2(
    const float* __restrict__ hmu, const float* __restrict__ hlv,
    const float* __restrict__ w2mu, const float* __restrict__ w2lv,
    float* __restrict__ gmu, float* __restrict__ glv,
    const float* __restrict__ m1p, const float* __restrict__ m2p,
    float* __restrict__ m1f, float* __restrict__ m2f)
{
    __shared__ float As[4][32][36];
    __shared__ float Bs[4][32][36];
    __shared__ float Cs[3][1024];

    const int b = blockIdx.x;
    const int tid = threadIdx.x;

    if (b >= 384) {
        const float inv_b = 1.0f / (float)BSZ;
        for (int c = tid; c < 512; c += 256) {
            float s1 = 0.f, s2 = 0.f;
            #pragma unroll
            for (int p = 0; p < 6; ++p) { s1 += m1p[p * 512 + c]; s2 += m2p[p * 512 + c]; }
            m1f[c] = s1 * inv_b;
            m2f[c] = s2 * inv_b;
        }
        return;
    }

    const int branch = b >= 192;
    const int idx = branch ? b - 192 : b;
    const int m0 = (idx >> 4) * 32;
    const int n0 = (idx & 15) * 32;

    if (!branch)
        gemm_tile32<false>(hmu, w2mu, nullptr, gmu, m0, n0, As, Bs, Cs);
    else
        gemm_tile32<false>(hlv, w2lv, nullptr, glv, m0, n0, As, Bs, Cs);
}

// Kernel 3: elementwise epilogue + final reduction. 192 blocks x 256 threads,
// one float4 per thread (192*256*4 = 196608 elements), fence+counter
// last-block 192-partial reduce.
__global__ __launch_bounds__(256) void k_epi(
    const float* __restrict__ gmu, const float* __restrict__ glv,
    const float* __restrict__ b2mu, const float* __restrict__ b2lv,
    const float* __restrict__ y,
    const float* __restrict__ m1f, const float* __restrict__ m2f,
    double* __restrict__ partials, unsigned* __restrict__ ctr,
    float* __restrict__ out)
{
    __shared__ double wsum[4];
    __shared__ int lastFlag;
    const int tid = threadIdx.x;
    const int e4 = blockIdx.x * 256 + tid;   // float4 index
    const int col4 = e4 & 127;               // f4 col group in row

    float gm[4], gl[4], yv[4], bm[4], bl[4], v1[4], v2[4];
    *(float4*)gm = *(const float4*)&gmu[(size_t)e4 * 4];
    *(float4*)gl = *(const float4*)&glv[(size_t)e4 * 4];
    *(float4*)yv = *(const float4*)&y[(size_t)e4 * 4];
    *(float4*)bm = *(const float4*)&b2mu[col4 * 4];
    *(float4*)bl = *(const float4*)&b2lv[col4 * 4];
    *(float4*)v1 = *(const float4*)&m1f[col4 * 4];
    *(float4*)v2 = *(const float4*)&m2f[col4 * 4];

    float tsum = 0.f;
    #pragma unroll
    for (int j = 0; j < 4; ++j) {
        const float mu = gm[j] + bm[j];
        const float lv = tanhf(gl[j] + bl[j]);
        const float iv = expf(-lv);
        tsum += iv * ((yv[j] * yv[j] - v2[j]) + 2.f * mu * (v1[j] - yv[j]));
    }

    float s = tsum;
    #pragma unroll
    for (int off = 32; off > 0; off >>= 1) s += __shfl_down(s, off);
    if ((tid & 63) == 0) wsum[tid >> 6] = (double)s;
    __syncthreads();
    if (tid == 0) {
        partials[blockIdx.x] = wsum[0] + wsum[1] + wsum[2] + wsum[3];
        __threadfence();
        lastFlag = (atomicAdd(ctr, 1u) == 191u);
    }
    __syncthreads();

    if (lastFlag) {
        __threadfence();  // acquire: make all partials visible
        if (tid < 64) {
            double v = partials[tid] + partials[tid + 64] + partials[tid + 128];
            #pragma unroll
            for (int off = 32; off > 0; off >>= 1) v += __shfl_down(v, off);
            if (tid == 0) {
                // C0 = log1p(exp(-20)/383) — the broadcast-bug logsumexp constant
                const double C0 = 5.381602146862063e-12;
                out[0] = (float)(-0.5 * v / (double)BSZ - C0);
            }
        }
    }
}

extern "C" void kernel_launch(void* const* d_in, const int* in_sizes, int n_in,
                              void* d_out, int out_size, void* d_ws, size_t ws_size,
                              hipStream_t stream) {
    const float* x    = (const float*)d_in[0];
    const float* y    = (const float*)d_in[1];
    const float* w1mu = (const float*)d_in[2];
    const float* b1mu = (const float*)d_in[3];
    const float* w2mu = (const float*)d_in[4];
    const float* b2mu = (const float*)d_in[5];
    const float* w1lv = (const float*)d_in[6];
    const float* b1lv = (const float*)d_in[7];
    const float* w2lv = (const float*)d_in[8];
    const float* b2lv = (const float*)d_in[9];
    float* out = (float*)d_out;

    float* ws = (float*)d_ws;
    float* hmu = ws;
    float* hlv = ws + 196608;
    float* gmu = ws + 393216;
    float* glv = ws + 589824;
    float* m1p = ws + 786432;
    float* m2p = ws + 789504;
    float* m1f = ws + 792576;
    float* m2f = ws + 793088;
    double* partials = (double*)(ws + 793600);
    unsigned* ctr = (unsigned*)(ws + 793984);

    k_l1<<<390, 256, 0, stream>>>(x, w1mu, b1mu, w1lv, b1lv, y,
                                  hmu, hlv, m1p, m2p, ctr);
    k_l2<<<385, 256, 0, stream>>>(hmu, hlv, w2mu, w2lv, gmu, glv,
                                  m1p, m2p, m1f, m2f);
    k_epi<<<192, 256, 0, stream>>>(gmu, glv, b2mu, b2lv, y,
                                   m1f, m2f, partials, ctr, out);
}

// Round 3
// 111.997 us; speedup vs baseline: 1.1064x; 1.0393x over previous
//
#include <hip/hip_runtime.h>
#include <math.h>

#define DIM  512
#define H2   512
#define BSZ  384

// ---------------------------------------------------------------------------
// ws layout (floats):
//   hmu : 384*512  @ 0        relu(x@w1mu + b1mu)
//   hlv : 384*512  @ 196608
//   gmu : 384*512  @ 393216   hmu@w2mu (no bias)
//   glv : 384*512  @ 589824
//   m1p : 6*512    @ 786432   y column-sum partials
//   m2p : 6*512    @ 789504   y column-sumsq partials
//   m1f : 512      @ 792576   column means of y
//   m2f : 512      @ 793088   column mean-squares of y
//   part: 192 dbl  @ 793600   (byte 3174400, 8B aligned)
//   ctr : 1 uint   @ 793984   arrival counter (zeroed by K1 each launch)
//
// Round-3 structure = best measured pieces only:
//   K1: round-0 GEMM structure (32x64 tile, 2x4 micro, proven fastest) for
//       layer 1, both branches (192 blocks) + 6 y-moment blocks. 198x256.
//   K2: round-0 GEMM structure for layer 2 (192 blocks) + 1 block finalizing
//       y column means (round-2 addition, overlaps GEMM blocks). 193x256.
//   K3: round-2 epilogue (192 blocks, 7 float4 loads/thread, fused final
//       reduce via fence+counter — proven). 192x256.
// ---------------------------------------------------------------------------

template<bool RELU>
__device__ __forceinline__ void gemm_tile(
    const float* __restrict__ A, const float* __restrict__ B,
    const float* __restrict__ bias, float* __restrict__ C,
    int m0, int n0,
    float (*As)[34], float (*Bs)[64])
{
    const int tid = threadIdx.x;
    const int tx = tid & 15;        // col group: n0 + tx*4
    const int ty = tid >> 4;        // rows: m0 + ty*2 + {0,1}

    const int r_a  = tid >> 3;      // 0..31  A-tile row
    const int kg_a = tid & 7;       // 0..7   A-tile k-group (4 floats)
    const int kr_b = tid >> 4;      // 0..15  B-tile row (and +16)
    const int cg_b = tid & 15;      // 0..15  B-tile col group

    float acc[2][4] = {};

    float4 a_pf  = *(const float4*)&A[(size_t)(m0 + r_a) * 512 + kg_a * 4];
    float4 b_pf0 = *(const float4*)&B[(size_t)kr_b        * 512 + n0 + cg_b * 4];
    float4 b_pf1 = *(const float4*)&B[(size_t)(kr_b + 16) * 512 + n0 + cg_b * 4];

    for (int it = 0; it < 16; ++it) {
        __syncthreads();
        {
            float av[4];
            *(float4*)av = a_pf;
            #pragma unroll
            for (int j = 0; j < 4; ++j) As[kg_a * 4 + j][r_a] = av[j];
            *(float4*)&Bs[kr_b][cg_b * 4]      = b_pf0;
            *(float4*)&Bs[kr_b + 16][cg_b * 4] = b_pf1;
        }
        __syncthreads();

        if (it < 15) {  // next-iter loads; latency overlaps compute below
            const int k0n = (it + 1) * 32;
            a_pf  = *(const float4*)&A[(size_t)(m0 + r_a) * 512 + k0n + kg_a * 4];
            b_pf0 = *(const float4*)&B[(size_t)(k0n + kr_b)      * 512 + n0 + cg_b * 4];
            b_pf1 = *(const float4*)&B[(size_t)(k0n + kr_b + 16) * 512 + n0 + cg_b * 4];
        }

        #pragma unroll
        for (int kk = 0; kk < 32; ++kk) {
            const float a0 = As[kk][ty * 2 + 0];
            const float a1 = As[kk][ty * 2 + 1];
            const float4 bv = *(const float4*)&Bs[kk][tx * 4];
            acc[0][0] += a0 * bv.x; acc[0][1] += a0 * bv.y;
            acc[0][2] += a0 * bv.z; acc[0][3] += a0 * bv.w;
            acc[1][0] += a1 * bv.x; acc[1][1] += a1 * bv.y;
            acc[1][2] += a1 * bv.z; acc[1][3] += a1 * bv.w;
        }
    }

    float bb[4] = {0.f, 0.f, 0.f, 0.f};
    if (RELU) *(float4*)bb = *(const float4*)&bias[n0 + tx * 4];
    #pragma unroll
    for (int i = 0; i < 2; ++i) {
        float4 o;
        if (RELU) {
            o.x = fmaxf(acc[i][0] + bb[0], 0.f);
            o.y = fmaxf(acc[i][1] + bb[1], 0.f);
            o.z = fmaxf(acc[i][2] + bb[2], 0.f);
            o.w = fmaxf(acc[i][3] + bb[3], 0.f);
        } else {
            o.x = acc[i][0]; o.y = acc[i][1]; o.z = acc[i][2]; o.w = acc[i][3];
        }
        *(float4*)&C[(size_t)(m0 + ty * 2 + i) * 512 + n0 + tx * 4] = o;
    }
}

// Kernel 1: layer-1 GEMMs for both branches (blocks 0..191) + y column-moment
// partial blocks (192..197). Block 192 also zeroes the K3 arrival counter.
__global__ __launch_bounds__(256) void k_layer1(
    const float* __restrict__ x,
    const float* __restrict__ w1mu, const float* __restrict__ b1mu,
    const float* __restrict__ w1lv, const float* __restrict__ b1lv,
    const float* __restrict__ y,
    float* __restrict__ hmu, float* __restrict__ hlv,
    float* __restrict__ m1p, float* __restrict__ m2p,
    unsigned* __restrict__ ctr)
{
    __shared__ float As[32][34];
    __shared__ float Bs[32][64];

    const int b = blockIdx.x;
    const int tid = threadIdx.x;

    if (b >= 192) {
        __shared__ float r1[2][512];
        __shared__ float r2[2][512];
        const int sb = b - 192;
        if (sb == 0 && tid == 0) *ctr = 0u;   // reset K3 arrival counter
        const int c4 = tid & 127;
        const int rh = tid >> 7;
        const int r0 = sb * 64 + rh * 32;
        float s1[4] = {0.f, 0.f, 0.f, 0.f};
        float s2[4] = {0.f, 0.f, 0.f, 0.f};
        for (int r = 0; r < 32; ++r) {
            float v[4];
            *(float4*)v = *(const float4*)&y[(size_t)(r0 + r) * 512 + c4 * 4];
            #pragma unroll
            for (int j = 0; j < 4; ++j) { s1[j] += v[j]; s2[j] += v[j] * v[j]; }
        }
        #pragma unroll
        for (int j = 0; j < 4; ++j) { r1[rh][c4 * 4 + j] = s1[j]; r2[rh][c4 * 4 + j] = s2[j]; }
        __syncthreads();
        if (rh == 0) {
            float4 o1, o2;
            o1.x = s1[0] + r1[1][c4 * 4 + 0]; o1.y = s1[1] + r1[1][c4 * 4 + 1];
            o1.z = s1[2] + r1[1][c4 * 4 + 2]; o1.w = s1[3] + r1[1][c4 * 4 + 3];
            o2.x = s2[0] + r2[1][c4 * 4 + 0]; o2.y = s2[1] + r2[1][c4 * 4 + 1];
            o2.z = s2[2] + r2[1][c4 * 4 + 2]; o2.w = s2[3] + r2[1][c4 * 4 + 3];
            *(float4*)&m1p[sb * 512 + c4 * 4] = o1;
            *(float4*)&m2p[sb * 512 + c4 * 4] = o2;
        }
        return;
    }

    const int branch = b >= 96 ? 1 : 0;
    const int idx = branch ? b - 96 : b;
    const int m0 = (idx >> 3) * 32;   // 12 row tiles
    const int n0 = (idx & 7) * 64;    // 8 col tiles

    if (branch == 0)
        gemm_tile<true>(x, w1mu, b1mu, hmu, m0, n0, As, Bs);
    else
        gemm_tile<true>(x, w1lv, b1lv, hlv, m0, n0, As, Bs);
}

// Kernel 2: layer-2 GEMMs, raw (bias deferred to K3), 192 blocks, plus
// block 192 finalizing the y column means (overlaps GEMM blocks; 64 CUs
// are idle at 192 GEMM blocks anyway).
__global__ __launch_bounds__(256) void k_layer2(
    const float* __restrict__ hmu, const float* __restrict__ hlv,
    const float* __restrict__ w2mu, const float* __restrict__ w2lv,
    float* __restrict__ gmu, float* __restrict__ glv,
    const float* __restrict__ m1p, const float* __restrict__ m2p,
    float* __restrict__ m1f, float* __restrict__ m2f)
{
    __shared__ float As[32][34];
    __shared__ float Bs[32][64];

    const int b = blockIdx.x;
    const int tid = threadIdx.x;

    if (b >= 192) {
        const float inv_b = 1.0f / (float)BSZ;
        for (int c = tid; c < 512; c += 256) {
            float s1 = 0.f, s2 = 0.f;
            #pragma unroll
            for (int p = 0; p < 6; ++p) { s1 += m1p[p * 512 + c]; s2 += m2p[p * 512 + c]; }
            m1f[c] = s1 * inv_b;
            m2f[c] = s2 * inv_b;
        }
        return;
    }

    const int branch = b >= 96 ? 1 : 0;
    const int idx = branch ? b - 96 : b;
    const int m0 = (idx >> 3) * 32;
    const int n0 = (idx & 7) * 64;

    if (branch == 0)
        gemm_tile<false>(hmu, w2mu, nullptr, gmu, m0, n0, As, Bs);
    else
        gemm_tile<false>(hlv, w2lv, nullptr, glv, m0, n0, As, Bs);
}

// Kernel 3: elementwise epilogue + final reduction. 192 blocks x 256 threads,
// one float4 per thread (192*256*4 = 196608 elements), fence+counter
// last-block 192-partial reduce (proven in rounds 1-2).
__global__ __launch_bounds__(256) void k_epi(
    const float* __restrict__ gmu, const float* __restrict__ glv,
    const float* __restrict__ b2mu, const float* __restrict__ b2lv,
    const float* __restrict__ y,
    const float* __restrict__ m1f, const float* __restrict__ m2f,
    double* __restrict__ partials, unsigned* __restrict__ ctr,
    float* __restrict__ out)
{
    __shared__ double wsum[4];
    __shared__ int lastFlag;
    const int tid = threadIdx.x;
    const int e4 = blockIdx.x * 256 + tid;   // float4 index
    const int col4 = e4 & 127;               // f4 col group in row

    float gm[4], gl[4], yv[4], bm[4], bl[4], v1[4], v2[4];
    *(float4*)gm = *(const float4*)&gmu[(size_t)e4 * 4];
    *(float4*)gl = *(const float4*)&glv[(size_t)e4 * 4];
    *(float4*)yv = *(const float4*)&y[(size_t)e4 * 4];
    *(float4*)bm = *(const float4*)&b2mu[col4 * 4];
    *(float4*)bl = *(const float4*)&b2lv[col4 * 4];
    *(float4*)v1 = *(const float4*)&m1f[col4 * 4];
    *(float4*)v2 = *(const float4*)&m2f[col4 * 4];

    float tsum = 0.f;
    #pragma unroll
    for (int j = 0; j < 4; ++j) {
        const float mu = gm[j] + bm[j];
        const float lv = tanhf(gl[j] + bl[j]);
        const float iv = expf(-lv);
        tsum += iv * ((yv[j] * yv[j] - v2[j]) + 2.f * mu * (v1[j] - yv[j]));
    }

    float s = tsum;
    #pragma unroll
    for (int off = 32; off > 0; off >>= 1) s += __shfl_down(s, off);
    if ((tid & 63) == 0) wsum[tid >> 6] = (double)s;
    __syncthreads();
    if (tid == 0) {
        partials[blockIdx.x] = wsum[0] + wsum[1] + wsum[2] + wsum[3];
        __threadfence();
        lastFlag = (atomicAdd(ctr, 1u) == 191u);
    }
    __syncthreads();

    if (lastFlag) {
        __threadfence();  // acquire: make all partials visible
        if (tid < 64) {
            double v = partials[tid] + partials[tid + 64] + partials[tid + 128];
            #pragma unroll
            for (int off = 32; off > 0; off >>= 1) v += __shfl_down(v, off);
            if (tid == 0) {
                // C0 = log1p(exp(-20)/383) — the broadcast-bug logsumexp constant
                const double C0 = 5.381602146862063e-12;
                out[0] = (float)(-0.5 * v / (double)BSZ - C0);
            }
        }
    }
}

extern "C" void kernel_launch(void* const* d_in, const int* in_sizes, int n_in,
                              void* d_out, int out_size, void* d_ws, size_t ws_size,
                              hipStream_t stream) {
    const float* x    = (const float*)d_in[0];
    const float* y    = (const float*)d_in[1];
    const float* w1mu = (const float*)d_in[2];
    const float* b1mu = (const float*)d_in[3];
    const float* w2mu = (const float*)d_in[4];
    const float* b2mu = (const float*)d_in[5];
    const float* w1lv = (const float*)d_in[6];
    const float* b1lv = (const float*)d_in[7];
    const float* w2lv = (const float*)d_in[8];
    const float* b2lv = (const float*)d_in[9];
    float* out = (float*)d_out;

    float* ws = (float*)d_ws;
    float* hmu = ws;
    float* hlv = ws + 196608;
    float* gmu = ws + 393216;
    float* glv = ws + 589824;
    float* m1p = ws + 786432;
    float* m2p = ws + 789504;
    float* m1f = ws + 792576;
    float* m2f = ws + 793088;
    double* partials = (double*)(ws + 793600);
    unsigned* ctr = (unsigned*)(ws + 793984);

    k_layer1<<<198, 256, 0, stream>>>(x, w1mu, b1mu, w1lv, b1lv, y,
                                      hmu, hlv, m1p, m2p, ctr);
    k_layer2<<<193, 256, 0, stream>>>(hmu, hlv, w2mu, w2lv, gmu, glv,
                                      m1p, m2p, m1f, m2f);
    k_epi<<<192, 256, 0, stream>>>(gmu, glv, b2mu, b2lv, y,
                                   m1f, m2f, partials, ctr, out);
}